// Round 7
// baseline (523.166 us; speedup 1.0000x reference)
//
#include <hip/hip_runtime.h>

#define NN 512       // nodes
#define BB_ 64       // batch
#define EE 32768     // edges
#define TT 50        // input channels
#define FF 32        // hidden channels
#define NB 2048      // BB_*FF : width of node-major feature rows

// ws float offsets
#define OFF_LHAT 0
#define OFF_DEG  (512 * 512)
#define OFF_H    (OFF_DEG + 512)
#define OFF_G    (OFF_H + NN * NB)
#define OFF_F0   (OFF_G + NN * NB)
#define WS_FLOATS (OFF_F0 + NN * NB)
// P (fc1 partials, 128*64*256 = 2M floats = 8MB) aliases G+F0 (dead at fc1 time)

// ---------------- setup kernels ----------------

__global__ void k_zero_out(float* out, int n) {
    int i = blockIdx.x * blockDim.x + threadIdx.x;
    if (i < n) out[i] = 0.f;
}

__global__ void k_zero_range(float* p, int n) {
    int i = blockIdx.x * blockDim.x + threadIdx.x;
    if (i < n) p[i] = 0.f;
}

__global__ void k_deg(const int* __restrict__ ei, const float* __restrict__ ew,
                      float* __restrict__ deg) {
    int e = blockIdx.x * blockDim.x + threadIdx.x;
    if (e >= EE) return;
    int s = ei[e] & (NN - 1), d = ei[EE + e] & (NN - 1);
    if (s != d) atomicAdd(&deg[s], ew[e]);
}

__global__ void k_dinv(float* deg) {
    int i = threadIdx.x;
    float d = deg[i];
    deg[i] = (d > 0.f) ? rsqrtf(d) : 0.f;
}

__global__ void k_build(const int* __restrict__ ei, const float* __restrict__ ew,
                        const float* __restrict__ dinv, float* __restrict__ Lhat) {
    int e = blockIdx.x * blockDim.x + threadIdx.x;
    if (e >= EE) return;
    int s = ei[e] & (NN - 1), d = ei[EE + e] & (NN - 1);
    if (s == d) return;
    float nm = -(dinv[s] * ew[e] * dinv[d]);
    atomicAdd(&Lhat[d * NN + s], nm);
}

// ---------------- small GEMM: G = H W1, F0 = H W0 + b ----------------
// node-major rows r = n*64+b. 64 rows/block, grid 512, block 256 = 8 rowslots x 32 f.
template<int CIN, bool FROM_X>
__global__ __launch_bounds__(256) void k_small(
        const float* __restrict__ Hin, const float* __restrict__ W,
        const float* __restrict__ bias,
        float* __restrict__ G, float* __restrict__ F0) {
    __shared__ float W0s[CIN * FF];
    __shared__ float W1s[CIN * FF];
    __shared__ float bs[FF];
    __shared__ float rows[64][CIN];
    const int tid = threadIdx.x;
    for (int i = tid; i < CIN * FF; i += 256) {
        W0s[i] = W[i];
        W1s[i] = W[CIN * FF + i];
    }
    if (tid < FF) bs[tid] = bias[tid];
    const int r0 = blockIdx.x * 64;
    for (int idx = tid; idx < 64 * CIN; idx += 256) {
        int r = idx / CIN, c = idx % CIN;
        int R = r0 + r;
        rows[r][c] = FROM_X ? Hin[((size_t)(R & 63) * NN + (R >> 6)) * CIN + c]
                            : Hin[(size_t)R * CIN + c];
    }
    __syncthreads();
    const int f = tid & 31, g = tid >> 5;
    float gacc[8] = {};
    float facc[8];
#pragma unroll
    for (int i = 0; i < 8; ++i) facc[i] = bs[f];
    for (int c = 0; c < CIN; ++c) {
        float w0 = W0s[c * FF + f], w1 = W1s[c * FF + f];
#pragma unroll
        for (int i = 0; i < 8; ++i) {
            float hv = rows[g + 8 * i][c];
            gacc[i] = fmaf(hv, w1, gacc[i]);
            facc[i] = fmaf(hv, w0, facc[i]);
        }
    }
#pragma unroll
    for (int i = 0; i < 8; ++i) {
        size_t o = (size_t)(r0 + g + 8 * i) * FF + f;
        G[o] = gacc[i];
        F0[o] = facc[i];
    }
}

// ---------------- big GEMM: H = [relu](Lhat @ G + F0) ----------------
// v3: lane = output row (64 rows/block), wave = 16-column stripe.
// B-operand (G) is wave-uniform -> broadcast loads, NO LDS for B.
// A staged in LDS double-buffered, 1 barrier per 32-k stage.
// grid (2048/64=32, 512/64=8) = 256 blocks, 256 threads (4 waves).
template<bool RELU>
__global__ __launch_bounds__(256) void k_prop(
        const float* __restrict__ L, const float* __restrict__ G,
        const float* __restrict__ F0, float* __restrict__ H) {
    __shared__ float As[2][32][64];   // [buf][k][row]
    __shared__ float T[64][68];       // epilogue transpose (row stride 68: f4-aligned)
    const int tid  = threadIdx.x;
    const int lane = tid & 63;
    const int w    = tid >> 6;                 // wave 0..3
    const int i0   = blockIdx.y * 64;
    const int j0   = blockIdx.x * 64;
    const int jw   = j0 + __builtin_amdgcn_readfirstlane(w) * 16;

    const int ar  = lane;                      // staged row
    const int ac0 = w * 8;                     // staged k-cols [ac0, ac0+8)
    const float* Lrow = L + (size_t)(i0 + ar) * NN + ac0;

    float acc[16] = {};

    // prologue: stage 0 -> buf 0
    float4 p0 = *(const float4*)&Lrow[0];
    float4 p1 = *(const float4*)&Lrow[4];
    As[0][ac0 + 0][ar] = p0.x; As[0][ac0 + 1][ar] = p0.y;
    As[0][ac0 + 2][ar] = p0.z; As[0][ac0 + 3][ar] = p0.w;
    As[0][ac0 + 4][ar] = p1.x; As[0][ac0 + 5][ar] = p1.y;
    As[0][ac0 + 6][ar] = p1.z; As[0][ac0 + 7][ar] = p1.w;
    __syncthreads();

    for (int s = 0; s < 16; ++s) {
        const int buf = s & 1;
        if (s < 15) {                          // prefetch next stage into regs
            p0 = *(const float4*)&Lrow[(s + 1) * 32];
            p1 = *(const float4*)&Lrow[(s + 1) * 32 + 4];
        }
        const float* gp = G + (size_t)(s * 32) * NB + jw;
#pragma unroll 8
        for (int k = 0; k < 32; ++k) {
            const float vA = As[buf][k][lane];
            const float4 b0 = *(const float4*)&gp[(size_t)k * NB + 0];
            const float4 b1 = *(const float4*)&gp[(size_t)k * NB + 4];
            const float4 b2 = *(const float4*)&gp[(size_t)k * NB + 8];
            const float4 b3 = *(const float4*)&gp[(size_t)k * NB + 12];
            acc[ 0] = fmaf(vA, b0.x, acc[ 0]); acc[ 1] = fmaf(vA, b0.y, acc[ 1]);
            acc[ 2] = fmaf(vA, b0.z, acc[ 2]); acc[ 3] = fmaf(vA, b0.w, acc[ 3]);
            acc[ 4] = fmaf(vA, b1.x, acc[ 4]); acc[ 5] = fmaf(vA, b1.y, acc[ 5]);
            acc[ 6] = fmaf(vA, b1.z, acc[ 6]); acc[ 7] = fmaf(vA, b1.w, acc[ 7]);
            acc[ 8] = fmaf(vA, b2.x, acc[ 8]); acc[ 9] = fmaf(vA, b2.y, acc[ 9]);
            acc[10] = fmaf(vA, b2.z, acc[10]); acc[11] = fmaf(vA, b2.w, acc[11]);
            acc[12] = fmaf(vA, b3.x, acc[12]); acc[13] = fmaf(vA, b3.y, acc[13]);
            acc[14] = fmaf(vA, b3.z, acc[14]); acc[15] = fmaf(vA, b3.w, acc[15]);
        }
        if (s < 15) {
            const int nb = buf ^ 1;
            As[nb][ac0 + 0][ar] = p0.x; As[nb][ac0 + 1][ar] = p0.y;
            As[nb][ac0 + 2][ar] = p0.z; As[nb][ac0 + 3][ar] = p0.w;
            As[nb][ac0 + 4][ar] = p1.x; As[nb][ac0 + 5][ar] = p1.y;
            As[nb][ac0 + 6][ar] = p1.z; As[nb][ac0 + 7][ar] = p1.w;
        }
        __syncthreads();
    }

    // epilogue: transpose through LDS for coalesced stores
#pragma unroll
    for (int m = 0; m < 4; ++m) {
        float4 v; v.x = acc[4 * m]; v.y = acc[4 * m + 1];
        v.z = acc[4 * m + 2]; v.w = acc[4 * m + 3];
        *(float4*)&T[lane][w * 16 + 4 * m] = v;
    }
    __syncthreads();
#pragma unroll
    for (int rep = 0; rep < 4; ++rep) {
        const int ed = rep * 1024 + tid * 4;
        const int r = ed >> 6, c = ed & 63;
        float4 v = *(const float4*)&T[r][c];
        const size_t o = (size_t)(i0 + r) * NB + j0 + c;
        float4 f = *(const float4*)&F0[o];
        v.x += f.x; v.y += f.y; v.z += f.z; v.w += f.w;
        if (RELU) {
            v.x = fmaxf(v.x, 0.f); v.y = fmaxf(v.y, 0.f);
            v.z = fmaxf(v.z, 0.f); v.w = fmaxf(v.w, 0.f);
        }
        *(float4*)&H[o] = v;
    }
}

// ---------------- FC1: out = A(64x16384) @ W(16384x256), K-split partials ----
// grid (8 col-groups of 32, 128 K-chunks of 128). Block 256 = 32 j x 8 bq.
// A[b][k], k = n*32+f  ->  h[n][b][f]; chunk = 4 nodes = 8192 contiguous floats.
// Writes P[kc][b][j] partials (no atomics); reduced in k_fc23.
__global__ __launch_bounds__(256) void k_fc1(const float* __restrict__ h,
                                             const float* __restrict__ W,
                                             float* __restrict__ P) {
    __shared__ float AT[128][68];      // AT[k][b]
    const int tid = threadIdx.x;
    const int jg = blockIdx.x;         // 0..7
    const int kc = blockIdx.y;         // 0..127
    const float* hs = h + (size_t)kc * 4 * NB;
#pragma unroll
    for (int i = 0; i < 8; ++i) {
        int q = tid + i * 256;         // float4 index, 0..2047
        float4 v = *(const float4*)&hs[q * 4];
        int flat = q * 4;
        int nn = flat >> 11, rem = flat & 2047;
        int b = rem >> 5, f0 = rem & 31;
        int krow = nn * 32 + f0;
        AT[krow + 0][b] = v.x; AT[krow + 1][b] = v.y;
        AT[krow + 2][b] = v.z; AT[krow + 3][b] = v.w;
    }
    __syncthreads();
    const int tj = tid & 31, bq = tid >> 5;
    float acc[8] = {};
    const float* wp = W + (size_t)(kc * 128) * 256 + jg * 32 + tj;
#pragma unroll 8
    for (int k = 0; k < 128; ++k) {
        float w = wp[(size_t)k * 256];
        const float* ap = &AT[k][bq * 8];
        float4 a0 = *(const float4*)ap;
        float4 a1 = *(const float4*)(ap + 4);
        acc[0] = fmaf(a0.x, w, acc[0]); acc[1] = fmaf(a0.y, w, acc[1]);
        acc[2] = fmaf(a0.z, w, acc[2]); acc[3] = fmaf(a0.w, w, acc[3]);
        acc[4] = fmaf(a1.x, w, acc[4]); acc[5] = fmaf(a1.y, w, acc[5]);
        acc[6] = fmaf(a1.z, w, acc[6]); acc[7] = fmaf(a1.w, w, acc[7]);
    }
#pragma unroll
    for (int b2 = 0; b2 < 8; ++b2)
        P[(size_t)kc * 16384 + (bq * 8 + b2) * 256 + jg * 32 + tj] = acc[b2];
}

// ---------------- fused reduce + FC2 + FC3 ----------------
// grid 64 (batch); block 128. Reduces fc1 partials, folds fc1 bias.
__global__ __launch_bounds__(128) void k_fc23(const float* __restrict__ P,
        const float* __restrict__ b1, const float* __restrict__ W2,
        const float* __restrict__ b2, const float* __restrict__ W3,
        const float* __restrict__ b3, float* __restrict__ out) {
    __shared__ float row[256];
    __shared__ float r2[128];
    const int m = blockIdx.x, j = threadIdx.x;
#pragma unroll
    for (int rep = 0; rep < 2; ++rep) {
        int k2 = j + rep * 128;
        float s = b1[k2];
#pragma unroll 8
        for (int kc = 0; kc < 128; ++kc)
            s += P[(size_t)kc * 16384 + m * 256 + k2];
        row[k2] = s;
    }
    __syncthreads();
    float acc = b2[j];
#pragma unroll 4
    for (int k = 0; k < 256; ++k)
        acc = fmaf(row[k], W2[k * 128 + j], acc);
    r2[j] = acc;
    __syncthreads();
    const int w = j >> 6, l = j & 63;
    float s2 = r2[l] * W3[l * 2 + w] + r2[l + 64] * W3[(l + 64) * 2 + w];
#pragma unroll
    for (int off = 32; off > 0; off >>= 1)
        s2 += __shfl_down(s2, off);
    if (l == 0) out[m * 2 + w] = s2 + b3[w];
}

// ---------------- launch ----------------

extern "C" void kernel_launch(void* const* d_in, const int* in_sizes, int n_in,
                              void* d_out, int out_size, void* d_ws, size_t ws_size,
                              hipStream_t stream) {
    float* outp = (float*)d_out;
    if (ws_size < (size_t)WS_FLOATS * sizeof(float)) {
        k_zero_out<<<(out_size + 255) / 256, 256, 0, stream>>>(outp, out_size);
        return;
    }

    const float* x  = (const float*)d_in[0];
    const int*   ei = (const int*)d_in[1];
    const float* ew = (const float*)d_in[2];
    const float* cW[6] = {(const float*)d_in[3], (const float*)d_in[5],
                          (const float*)d_in[7], (const float*)d_in[9],
                          (const float*)d_in[11], (const float*)d_in[13]};
    const float* cb[6] = {(const float*)d_in[4], (const float*)d_in[6],
                          (const float*)d_in[8], (const float*)d_in[10],
                          (const float*)d_in[12], (const float*)d_in[14]};
    const float* fc1W = (const float*)d_in[15];
    const float* fc1b = (const float*)d_in[16];
    const float* fc2W = (const float*)d_in[17];
    const float* fc2b = (const float*)d_in[18];
    const float* fc3W = (const float*)d_in[19];
    const float* fc3b = (const float*)d_in[20];

    float* ws   = (float*)d_ws;
    float* Lhat = ws + OFF_LHAT;
    float* deg  = ws + OFF_DEG;
    float* H    = ws + OFF_H;
    float* G    = ws + OFF_G;
    float* F0   = ws + OFF_F0;
    float* P    = ws + OFF_G;   // fc1 partials alias G+F0 (8MB, dead then)

    // build dense Lhat
    k_zero_range<<<(OFF_DEG + 512 + 255) / 256, 256, 0, stream>>>(ws, OFF_DEG + 512);
    k_deg<<<EE / 256, 256, 0, stream>>>(ei, ew, deg);
    k_dinv<<<1, 512, 0, stream>>>(deg);
    k_build<<<EE / 256, 256, 0, stream>>>(ei, ew, deg, Lhat);

    dim3 pgrid(32, 8);
    // layer 1 (CIN=50, from x)
    k_small<TT, true ><<<512, 256, 0, stream>>>(x, cW[0], cb[0], G, F0);
    k_prop<true ><<<pgrid, 256, 0, stream>>>(Lhat, G, F0, H);
    // layers 2..5
    k_small<FF, false><<<512, 256, 0, stream>>>(H, cW[1], cb[1], G, F0);
    k_prop<true ><<<pgrid, 256, 0, stream>>>(Lhat, G, F0, H);
    k_small<FF, false><<<512, 256, 0, stream>>>(H, cW[2], cb[2], G, F0);
    k_prop<true ><<<pgrid, 256, 0, stream>>>(Lhat, G, F0, H);
    k_small<FF, false><<<512, 256, 0, stream>>>(H, cW[3], cb[3], G, F0);
    k_prop<true ><<<pgrid, 256, 0, stream>>>(Lhat, G, F0, H);
    k_small<FF, false><<<512, 256, 0, stream>>>(H, cW[4], cb[4], G, F0);
    k_prop<true ><<<pgrid, 256, 0, stream>>>(Lhat, G, F0, H);
    // layer 6 (no relu)
    k_small<FF, false><<<512, 256, 0, stream>>>(H, cW[5], cb[5], G, F0);
    k_prop<false><<<pgrid, 256, 0, stream>>>(Lhat, G, F0, H);

    // FC head
    dim3 fgrid(8, 128);
    k_fc1<<<fgrid, 256, 0, stream>>>(H, fc1W, P);
    k_fc23<<<64, 128, 0, stream>>>(P, fc1b, fc2W, fc2b, fc3W, fc3b, outp);
}

// Round 8
// 354.373 us; speedup vs baseline: 1.4763x; 1.4763x over previous
//
#include <hip/hip_runtime.h>

#define NN 512       // nodes
#define BB_ 64       // batch
#define EE 32768     // edges
#define TT 50        // input channels
#define FF 32        // hidden channels
#define NB 2048      // BB_*FF : width of node-major feature rows

// ws float offsets
#define OFF_LHAT 0
#define OFF_DEG  (512 * 512)
#define OFF_H    (OFF_DEG + 512)
#define OFF_G    (OFF_H + NN * NB)
#define OFF_F0   (OFF_G + NN * NB)
#define WS_FLOATS (OFF_F0 + NN * NB)
// P (fc1 partials, 128*64*256 = 2M floats = 8MB) aliases G+F0 (dead at fc1 time)

// ---------------- setup kernels ----------------

__global__ void k_zero_out(float* out, int n) {
    int i = blockIdx.x * blockDim.x + threadIdx.x;
    if (i < n) out[i] = 0.f;
}

__global__ void k_zero_range(float* p, int n) {
    int i = blockIdx.x * blockDim.x + threadIdx.x;
    if (i < n) p[i] = 0.f;
}

__global__ void k_deg(const int* __restrict__ ei, const float* __restrict__ ew,
                      float* __restrict__ deg) {
    int e = blockIdx.x * blockDim.x + threadIdx.x;
    if (e >= EE) return;
    int s = ei[e] & (NN - 1), d = ei[EE + e] & (NN - 1);
    if (s != d) atomicAdd(&deg[s], ew[e]);
}

__global__ void k_dinv(float* deg) {
    int i = threadIdx.x;
    float d = deg[i];
    deg[i] = (d > 0.f) ? rsqrtf(d) : 0.f;
}

__global__ void k_build(const int* __restrict__ ei, const float* __restrict__ ew,
                        const float* __restrict__ dinv, float* __restrict__ Lhat) {
    int e = blockIdx.x * blockDim.x + threadIdx.x;
    if (e >= EE) return;
    int s = ei[e] & (NN - 1), d = ei[EE + e] & (NN - 1);
    if (s == d) return;
    float nm = -(dinv[s] * ew[e] * dinv[d]);
    atomicAdd(&Lhat[d * NN + s], nm);
}

// ---------------- small GEMM: G = H W1, F0 = H W0 + b ----------------
// node-major rows r = n*64+b. 64 rows/block, grid 512, block 256 = 8 rowslots x 32 f.
template<int CIN, bool FROM_X>
__global__ __launch_bounds__(256) void k_small(
        const float* __restrict__ Hin, const float* __restrict__ W,
        const float* __restrict__ bias,
        float* __restrict__ G, float* __restrict__ F0) {
    __shared__ float W0s[CIN * FF];
    __shared__ float W1s[CIN * FF];
    __shared__ float bs[FF];
    __shared__ float rows[64][CIN];
    const int tid = threadIdx.x;
    for (int i = tid; i < CIN * FF; i += 256) {
        W0s[i] = W[i];
        W1s[i] = W[CIN * FF + i];
    }
    if (tid < FF) bs[tid] = bias[tid];
    const int r0 = blockIdx.x * 64;
    for (int idx = tid; idx < 64 * CIN; idx += 256) {
        int r = idx / CIN, c = idx % CIN;
        int R = r0 + r;
        rows[r][c] = FROM_X ? Hin[((size_t)(R & 63) * NN + (R >> 6)) * CIN + c]
                            : Hin[(size_t)R * CIN + c];
    }
    __syncthreads();
    const int f = tid & 31, g = tid >> 5;
    float gacc[8] = {};
    float facc[8];
#pragma unroll
    for (int i = 0; i < 8; ++i) facc[i] = bs[f];
    for (int c = 0; c < CIN; ++c) {
        float w0 = W0s[c * FF + f], w1 = W1s[c * FF + f];
#pragma unroll
        for (int i = 0; i < 8; ++i) {
            float hv = rows[g + 8 * i][c];
            gacc[i] = fmaf(hv, w1, gacc[i]);
            facc[i] = fmaf(hv, w0, facc[i]);
        }
    }
#pragma unroll
    for (int i = 0; i < 8; ++i) {
        size_t o = (size_t)(r0 + g + 8 * i) * FF + f;
        G[o] = gacc[i];
        F0[o] = facc[i];
    }
}

// ---------------- big GEMM: H = [relu](Lhat @ G + F0) ----------------
// v4: classic 64x64 tile, 256 threads, 4x4 per thread, K-step 16,
// single-barrier double-buffered LDS, all frags via ds_read_b128.
// grid (2048/64=32, 512/64=8) = 256 blocks.
template<bool RELU>
__global__ __launch_bounds__(256) void k_prop(
        const float* __restrict__ L, const float* __restrict__ G,
        const float* __restrict__ F0, float* __restrict__ H) {
    __shared__ float As[2][16][68];   // As[buf][k][i]  (i = row in tile)
    __shared__ float Bs[2][16][68];   // Bs[buf][k][j]
    const int tid = threadIdx.x;
    const int tx = tid & 15, ty = tid >> 4;
    const int i0 = blockIdx.y * 64, j0 = blockIdx.x * 64;
    const int ar = tid >> 2, ac = (tid & 3) * 4;   // A stage: row 0..63, kcol {0,4,8,12}
    const int bk = tid >> 4, bj = (tid & 15) * 4;  // B stage: krow 0..15, col {0..60}
    const float* Lp = L + (size_t)(i0 + ar) * NN + ac;
    const float* Gp = G + (size_t)bk * NB + j0 + bj;

    float acc[4][4] = {};
    float4 pa = *(const float4*)Lp;        // prologue: tile 0 in regs
    float4 pb = *(const float4*)Gp;

    for (int t = 0; t < 32; ++t) {
        const int buf = t & 1;
        // store tile t (in regs) into buf; safe: others still computing t-1
        // read buf^1 only.
        As[buf][ac + 0][ar] = pa.x; As[buf][ac + 1][ar] = pa.y;
        As[buf][ac + 2][ar] = pa.z; As[buf][ac + 3][ar] = pa.w;
        *(float4*)&Bs[buf][bk][bj] = pb;
        __syncthreads();
        if (t < 31) {                      // prefetch tile t+1 under compute
            pa = *(const float4*)(Lp + (t + 1) * 16);
            pb = *(const float4*)(Gp + (size_t)(t + 1) * 16 * NB);
        }
#pragma unroll
        for (int k = 0; k < 16; ++k) {
            float a[4], b[4];
            *(float4*)a = *(const float4*)&As[buf][k][ty * 4];
            *(float4*)b = *(const float4*)&Bs[buf][k][tx * 4];
#pragma unroll
            for (int m = 0; m < 4; ++m) {
#pragma unroll
                for (int q = 0; q < 4; ++q)
                    acc[m][q] = fmaf(a[m], b[q], acc[m][q]);
            }
        }
    }

    // epilogue: direct coalesced stores
#pragma unroll
    for (int m = 0; m < 4; ++m) {
        const size_t o = (size_t)(i0 + ty * 4 + m) * NB + j0 + tx * 4;
        float4 f0 = *(const float4*)&F0[o];
        float4 v;
        v.x = acc[m][0] + f0.x; v.y = acc[m][1] + f0.y;
        v.z = acc[m][2] + f0.z; v.w = acc[m][3] + f0.w;
        if (RELU) {
            v.x = fmaxf(v.x, 0.f); v.y = fmaxf(v.y, 0.f);
            v.z = fmaxf(v.z, 0.f); v.w = fmaxf(v.w, 0.f);
        }
        *(float4*)&H[o] = v;
    }
}

// ---------------- FC1: out = A(64x16384) @ W(16384x256), K-split partials ----
// grid (8 col-groups of 32, 128 K-chunks of 128). Block 256 = 32 j x 8 bq.
// A[b][k], k = n*32+f  ->  h[n][b][f]; chunk = 4 nodes = 8192 contiguous floats.
// Writes P[kc][b][j] partials (no atomics); reduced in k_fc23.
__global__ __launch_bounds__(256) void k_fc1(const float* __restrict__ h,
                                             const float* __restrict__ W,
                                             float* __restrict__ P) {
    __shared__ float AT[128][68];      // AT[k][b]
    const int tid = threadIdx.x;
    const int jg = blockIdx.x;         // 0..7
    const int kc = blockIdx.y;         // 0..127
    const float* hs = h + (size_t)kc * 4 * NB;
#pragma unroll
    for (int i = 0; i < 8; ++i) {
        int q = tid + i * 256;         // float4 index, 0..2047
        float4 v = *(const float4*)&hs[q * 4];
        int flat = q * 4;
        int nn = flat >> 11, rem = flat & 2047;
        int b = rem >> 5, f0 = rem & 31;
        int krow = nn * 32 + f0;
        AT[krow + 0][b] = v.x; AT[krow + 1][b] = v.y;
        AT[krow + 2][b] = v.z; AT[krow + 3][b] = v.w;
    }
    __syncthreads();
    const int tj = tid & 31, bq = tid >> 5;
    float acc[8] = {};
    const float* wp = W + (size_t)(kc * 128) * 256 + jg * 32 + tj;
#pragma unroll 8
    for (int k = 0; k < 128; ++k) {
        float w = wp[(size_t)k * 256];
        const float* ap = &AT[k][bq * 8];
        float4 a0 = *(const float4*)ap;
        float4 a1 = *(const float4*)(ap + 4);
        acc[0] = fmaf(a0.x, w, acc[0]); acc[1] = fmaf(a0.y, w, acc[1]);
        acc[2] = fmaf(a0.z, w, acc[2]); acc[3] = fmaf(a0.w, w, acc[3]);
        acc[4] = fmaf(a1.x, w, acc[4]); acc[5] = fmaf(a1.y, w, acc[5]);
        acc[6] = fmaf(a1.z, w, acc[6]); acc[7] = fmaf(a1.w, w, acc[7]);
    }
#pragma unroll
    for (int b2 = 0; b2 < 8; ++b2)
        P[(size_t)kc * 16384 + (bq * 8 + b2) * 256 + jg * 32 + tj] = acc[b2];
}

// ---------------- fused reduce + FC2 + FC3 ----------------
// grid 64 (batch); block 128. Reduces fc1 partials, folds fc1 bias.
__global__ __launch_bounds__(128) void k_fc23(const float* __restrict__ P,
        const float* __restrict__ b1, const float* __restrict__ W2,
        const float* __restrict__ b2, const float* __restrict__ W3,
        const float* __restrict__ b3, float* __restrict__ out) {
    __shared__ float row[256];
    __shared__ float r2[128];
    const int m = blockIdx.x, j = threadIdx.x;
#pragma unroll
    for (int rep = 0; rep < 2; ++rep) {
        int k2 = j + rep * 128;
        float s = b1[k2];
#pragma unroll 8
        for (int kc = 0; kc < 128; ++kc)
            s += P[(size_t)kc * 16384 + m * 256 + k2];
        row[k2] = s;
    }
    __syncthreads();
    float acc = b2[j];
#pragma unroll 4
    for (int k = 0; k < 256; ++k)
        acc = fmaf(row[k], W2[k * 128 + j], acc);
    r2[j] = acc;
    __syncthreads();
    const int w = j >> 6, l = j & 63;
    float s2 = r2[l] * W3[l * 2 + w] + r2[l + 64] * W3[(l + 64) * 2 + w];
#pragma unroll
    for (int off = 32; off > 0; off >>= 1)
        s2 += __shfl_down(s2, off);
    if (l == 0) out[m * 2 + w] = s2 + b3[w];
}

// ---------------- launch ----------------

extern "C" void kernel_launch(void* const* d_in, const int* in_sizes, int n_in,
                              void* d_out, int out_size, void* d_ws, size_t ws_size,
                              hipStream_t stream) {
    float* outp = (float*)d_out;
    if (ws_size < (size_t)WS_FLOATS * sizeof(float)) {
        k_zero_out<<<(out_size + 255) / 256, 256, 0, stream>>>(outp, out_size);
        return;
    }

    const float* x  = (const float*)d_in[0];
    const int*   ei = (const int*)d_in[1];
    const float* ew = (const float*)d_in[2];
    const float* cW[6] = {(const float*)d_in[3], (const float*)d_in[5],
                          (const float*)d_in[7], (const float*)d_in[9],
                          (const float*)d_in[11], (const float*)d_in[13]};
    const float* cb[6] = {(const float*)d_in[4], (const float*)d_in[6],
                          (const float*)d_in[8], (const float*)d_in[10],
                          (const float*)d_in[12], (const float*)d_in[14]};
    const float* fc1W = (const float*)d_in[15];
    const float* fc1b = (const float*)d_in[16];
    const float* fc2W = (const float*)d_in[17];
    const float* fc2b = (const float*)d_in[18];
    const float* fc3W = (const float*)d_in[19];
    const float* fc3b = (const float*)d_in[20];

    float* ws   = (float*)d_ws;
    float* Lhat = ws + OFF_LHAT;
    float* deg  = ws + OFF_DEG;
    float* H    = ws + OFF_H;
    float* G    = ws + OFF_G;
    float* F0   = ws + OFF_F0;
    float* P    = ws + OFF_G;   // fc1 partials alias G+F0 (8MB, dead then)

    // build dense Lhat
    k_zero_range<<<(OFF_DEG + 512 + 255) / 256, 256, 0, stream>>>(ws, OFF_DEG + 512);
    k_deg<<<EE / 256, 256, 0, stream>>>(ei, ew, deg);
    k_dinv<<<1, 512, 0, stream>>>(deg);
    k_build<<<EE / 256, 256, 0, stream>>>(ei, ew, deg, Lhat);

    dim3 pgrid(32, 8);
    // layer 1 (CIN=50, from x)
    k_small<TT, true ><<<512, 256, 0, stream>>>(x, cW[0], cb[0], G, F0);
    k_prop<true ><<<pgrid, 256, 0, stream>>>(Lhat, G, F0, H);
    // layers 2..5
    k_small<FF, false><<<512, 256, 0, stream>>>(H, cW[1], cb[1], G, F0);
    k_prop<true ><<<pgrid, 256, 0, stream>>>(Lhat, G, F0, H);
    k_small<FF, false><<<512, 256, 0, stream>>>(H, cW[2], cb[2], G, F0);
    k_prop<true ><<<pgrid, 256, 0, stream>>>(Lhat, G, F0, H);
    k_small<FF, false><<<512, 256, 0, stream>>>(H, cW[3], cb[3], G, F0);
    k_prop<true ><<<pgrid, 256, 0, stream>>>(Lhat, G, F0, H);
    k_small<FF, false><<<512, 256, 0, stream>>>(H, cW[4], cb[4], G, F0);
    k_prop<true ><<<pgrid, 256, 0, stream>>>(Lhat, G, F0, H);
    // layer 6 (no relu)
    k_small<FF, false><<<512, 256, 0, stream>>>(H, cW[5], cb[5], G, F0);
    k_prop<false><<<pgrid, 256, 0, stream>>>(Lhat, G, F0, H);

    // FC head
    dim3 fgrid(8, 128);
    k_fc1<<<fgrid, 256, 0, stream>>>(H, fc1W, P);
    k_fc23<<<64, 128, 0, stream>>>(P, fc1b, fc2W, fc2b, fc3W, fc3b, outp);
}

// Round 9
// 325.038 us; speedup vs baseline: 1.6096x; 1.0902x over previous
//
#include <hip/hip_runtime.h>

#define NN 512       // nodes
#define BB_ 64       // batch
#define EE 32768     // edges
#define TT 50        // input channels
#define FF 32        // hidden channels
#define NB 2048      // BB_*FF : width of node-major feature rows

typedef _Float16 f16x8 __attribute__((ext_vector_type(8)));
typedef float    f32x4 __attribute__((ext_vector_type(4)));

// ws float offsets
#define OFF_LHAT 0
#define OFF_LP   (512 * 512)
#define OFF_DEG  (OFF_LP + 512 * 512)
#define OFF_HP0  (OFF_DEG + 512)
#define OFF_HP1  (OFF_HP0 + NN * NB)
#define OFF_GP   (OFF_HP1 + NN * NB)
#define OFF_F0   (OFF_GP + NN * NB)
#define WS_FLOATS (OFF_F0 + NN * NB)
// P (fc1 partials, 2M floats) aliases GP+F0 (dead at fc1 time)

__device__ __forceinline__ unsigned pack_split(float v) {
    _Float16 h = (_Float16)v;
    _Float16 l = (_Float16)(v - (float)h);
    return (unsigned)__builtin_bit_cast(unsigned short, h) |
           ((unsigned)__builtin_bit_cast(unsigned short, l) << 16);
}

// ---------------- setup kernels ----------------

__global__ void k_zero_out(float* out, int n) {
    int i = blockIdx.x * blockDim.x + threadIdx.x;
    if (i < n) out[i] = 0.f;
}

__global__ void k_zero_range(float* p, int n) {
    int i = blockIdx.x * blockDim.x + threadIdx.x;
    if (i < n) p[i] = 0.f;
}

__global__ void k_deg(const int* __restrict__ ei, const float* __restrict__ ew,
                      float* __restrict__ deg) {
    int e = blockIdx.x * blockDim.x + threadIdx.x;
    if (e >= EE) return;
    int s = ei[e] & (NN - 1), d = ei[EE + e] & (NN - 1);
    if (s != d) atomicAdd(&deg[s], ew[e]);
}

__global__ void k_dinv(float* deg) {
    int i = threadIdx.x;
    float d = deg[i];
    deg[i] = (d > 0.f) ? rsqrtf(d) : 0.f;
}

__global__ void k_build(const int* __restrict__ ei, const float* __restrict__ ew,
                        const float* __restrict__ dinv, float* __restrict__ Lhat) {
    int e = blockIdx.x * blockDim.x + threadIdx.x;
    if (e >= EE) return;
    int s = ei[e] & (NN - 1), d = ei[EE + e] & (NN - 1);
    if (s == d) return;
    float nm = -(dinv[s] * ew[e] * dinv[d]);
    atomicAdd(&Lhat[d * NN + s], nm);
}

__global__ void k_splitL(const float* __restrict__ L, unsigned* __restrict__ Lp) {
    int i = blockIdx.x * 256 + threadIdx.x;   // 262144 total
    Lp[i] = pack_split(L[i]);
}

// ---------------- small GEMM: Gp = split(H W1), F0 = H W0 + b ----------------
// MODE 0: input x[b][n][CIN];  MODE 1: input relu(Hp0+Hp1) node-major flat.
template<int CIN, int MODE>
__global__ __launch_bounds__(256) void k_small(
        const float* __restrict__ A0, const float* __restrict__ A1,
        const float* __restrict__ W, const float* __restrict__ bias,
        unsigned* __restrict__ Gp, float* __restrict__ F0) {
    __shared__ float W0s[CIN * FF];
    __shared__ float W1s[CIN * FF];
    __shared__ float bs[FF];
    __shared__ float rows[64][CIN];
    const int tid = threadIdx.x;
    for (int i = tid; i < CIN * FF; i += 256) {
        W0s[i] = W[i];
        W1s[i] = W[CIN * FF + i];
    }
    if (tid < FF) bs[tid] = bias[tid];
    const int r0 = blockIdx.x * 64;
    for (int idx = tid; idx < 64 * CIN; idx += 256) {
        int r = idx / CIN, c = idx % CIN;
        int R = r0 + r;
        float v;
        if (MODE == 0) {
            v = A0[((size_t)(R & 63) * NN + (R >> 6)) * CIN + c];
        } else {
            size_t o = (size_t)R * CIN + c;
            v = fmaxf(A0[o] + A1[o], 0.f);
        }
        rows[r][c] = v;
    }
    __syncthreads();
    const int f = tid & 31, g = tid >> 5;
    float gacc[8] = {};
    float facc[8];
#pragma unroll
    for (int i = 0; i < 8; ++i) facc[i] = bs[f];
    for (int c = 0; c < CIN; ++c) {
        float w0 = W0s[c * FF + f], w1 = W1s[c * FF + f];
#pragma unroll
        for (int i = 0; i < 8; ++i) {
            float hv = rows[g + 8 * i][c];
            gacc[i] = fmaf(hv, w1, gacc[i]);
            facc[i] = fmaf(hv, w0, facc[i]);
        }
    }
#pragma unroll
    for (int i = 0; i < 8; ++i) {
        size_t o = (size_t)(r0 + g + 8 * i) * FF + f;
        Gp[o] = pack_split(gacc[i]);
        F0[o] = facc[i];
    }
}

// ---------------- big GEMM via MFMA f16-split ----------------
// Hp_z = Lhat[:, zK..] @ G[zK.., :] (exact via hi/lo f16 4-product split),
// z==0 adds F0. Partials combined (+relu) by the consumer kernel.
// Block: 256 thr = 4 waves (2x2 of 32x32), tile 64x64, K-chunk 32 dbuf.
// grid (2048/64=32, 512/64=8, 2) = 512 blocks.
__global__ __launch_bounds__(256) void k_prop_mfma(
        const unsigned* __restrict__ Lp, const unsigned* __restrict__ Gp,
        const float* __restrict__ F0,
        float* __restrict__ Hp0, float* __restrict__ Hp1) {
    __shared__ unsigned short Ahi[2][64][40], Alo[2][64][40];
    __shared__ unsigned short Bhi[2][64][40], Blo[2][64][40];
    const int tid  = threadIdx.x;
    const int lane = tid & 63, w = tid >> 6;
    const int wm = w >> 1, wn = w & 1;
    const int grp = lane >> 4, l16 = lane & 15;
    const int i0 = blockIdx.y * 64, j0 = blockIdx.x * 64;
    const int kbase = blockIdx.z * 256;

    const int arow = tid >> 5, ak = tid & 31;     // A stage: +i*8 rows
    const int brow = tid >> 6, bcol = tid & 63;   // B stage: +i*4 krows

    f32x4 acc[2][2] = {};
    unsigned pa[8], pb[8];

    // prologue: chunk 0 -> regs
#pragma unroll
    for (int i = 0; i < 8; ++i)
        pa[i] = Lp[(size_t)(i0 + arow + i * 8) * NN + kbase + ak];
#pragma unroll
    for (int i = 0; i < 8; ++i)
        pb[i] = Gp[(size_t)(kbase + brow + i * 4) * NB + j0 + bcol];

    for (int t = 0; t < 8; ++t) {
        const int buf = t & 1;
#pragma unroll
        for (int i = 0; i < 8; ++i) {
            unsigned v = pa[i];
            Ahi[buf][arow + i * 8][ak] = (unsigned short)v;
            Alo[buf][arow + i * 8][ak] = (unsigned short)(v >> 16);
        }
#pragma unroll
        for (int i = 0; i < 8; ++i) {
            unsigned v = pb[i];
            Bhi[buf][bcol][brow + i * 4] = (unsigned short)v;
            Blo[buf][bcol][brow + i * 4] = (unsigned short)(v >> 16);
        }
        __syncthreads();
        if (t < 7) {
            const int kc = kbase + (t + 1) * 32;
#pragma unroll
            for (int i = 0; i < 8; ++i)
                pa[i] = Lp[(size_t)(i0 + arow + i * 8) * NN + kc + ak];
#pragma unroll
            for (int i = 0; i < 8; ++i)
                pb[i] = Gp[(size_t)(kc + brow + i * 4) * NB + j0 + bcol];
        }
        f16x8 ah[2], al[2], bh[2], bl[2];
#pragma unroll
        for (int mi = 0; mi < 2; ++mi) {
            ah[mi] = *(const f16x8*)&Ahi[buf][wm * 32 + mi * 16 + l16][grp * 8];
            al[mi] = *(const f16x8*)&Alo[buf][wm * 32 + mi * 16 + l16][grp * 8];
        }
#pragma unroll
        for (int ni = 0; ni < 2; ++ni) {
            bh[ni] = *(const f16x8*)&Bhi[buf][wn * 32 + ni * 16 + l16][grp * 8];
            bl[ni] = *(const f16x8*)&Blo[buf][wn * 32 + ni * 16 + l16][grp * 8];
        }
#pragma unroll
        for (int mi = 0; mi < 2; ++mi)
#pragma unroll
            for (int ni = 0; ni < 2; ++ni) {
                acc[mi][ni] = __builtin_amdgcn_mfma_f32_16x16x32_f16(al[mi], bl[ni], acc[mi][ni], 0, 0, 0);
                acc[mi][ni] = __builtin_amdgcn_mfma_f32_16x16x32_f16(al[mi], bh[ni], acc[mi][ni], 0, 0, 0);
                acc[mi][ni] = __builtin_amdgcn_mfma_f32_16x16x32_f16(ah[mi], bl[ni], acc[mi][ni], 0, 0, 0);
                acc[mi][ni] = __builtin_amdgcn_mfma_f32_16x16x32_f16(ah[mi], bh[ni], acc[mi][ni], 0, 0, 0);
            }
        __syncthreads();
    }

    // epilogue: C/D layout col=lane&15, row=(lane>>4)*4+reg [verified]
    float* Hp = blockIdx.z ? Hp1 : Hp0;
#pragma unroll
    for (int mi = 0; mi < 2; ++mi)
#pragma unroll
        for (int ni = 0; ni < 2; ++ni)
#pragma unroll
            for (int p = 0; p < 4; ++p) {
                const int row = i0 + wm * 32 + mi * 16 + grp * 4 + p;
                const int col = j0 + wn * 32 + ni * 16 + l16;
                const size_t idx = (size_t)row * NB + col;
                float v = acc[mi][ni][p];
                if (blockIdx.z == 0) v += F0[idx];
                Hp[idx] = v;
            }
}

// ---------------- FC1: out = A(64x16384) @ W(16384x256), K-split partials ----
// A = Hp0+Hp1 (no relu after conv6). Writes P[kc][b][j]; reduced in k_fc23.
__global__ __launch_bounds__(256) void k_fc1(const float* __restrict__ h0,
                                             const float* __restrict__ h1,
                                             const float* __restrict__ W,
                                             float* __restrict__ P) {
    __shared__ float AT[128][68];      // AT[k][b]
    const int tid = threadIdx.x;
    const int jg = blockIdx.x;         // 0..7
    const int kc = blockIdx.y;         // 0..127
    const size_t base = (size_t)kc * 4 * NB;
#pragma unroll
    for (int i = 0; i < 8; ++i) {
        int q = tid + i * 256;         // float4 index, 0..2047
        float4 v0 = *(const float4*)&h0[base + q * 4];
        float4 v1 = *(const float4*)&h1[base + q * 4];
        float4 v;
        v.x = v0.x + v1.x; v.y = v0.y + v1.y;
        v.z = v0.z + v1.z; v.w = v0.w + v1.w;
        int flat = q * 4;
        int nn = flat >> 11, rem = flat & 2047;
        int b = rem >> 5, f0 = rem & 31;
        int krow = nn * 32 + f0;
        AT[krow + 0][b] = v.x; AT[krow + 1][b] = v.y;
        AT[krow + 2][b] = v.z; AT[krow + 3][b] = v.w;
    }
    __syncthreads();
    const int tj = tid & 31, bq = tid >> 5;
    float acc[8] = {};
    const float* wp = W + (size_t)(kc * 128) * 256 + jg * 32 + tj;
#pragma unroll 8
    for (int k = 0; k < 128; ++k) {
        float w = wp[(size_t)k * 256];
        const float* ap = &AT[k][bq * 8];
        float4 a0 = *(const float4*)ap;
        float4 a1 = *(const float4*)(ap + 4);
        acc[0] = fmaf(a0.x, w, acc[0]); acc[1] = fmaf(a0.y, w, acc[1]);
        acc[2] = fmaf(a0.z, w, acc[2]); acc[3] = fmaf(a0.w, w, acc[3]);
        acc[4] = fmaf(a1.x, w, acc[4]); acc[5] = fmaf(a1.y, w, acc[5]);
        acc[6] = fmaf(a1.z, w, acc[6]); acc[7] = fmaf(a1.w, w, acc[7]);
    }
#pragma unroll
    for (int b2 = 0; b2 < 8; ++b2)
        P[(size_t)kc * 16384 + (bq * 8 + b2) * 256 + jg * 32 + tj] = acc[b2];
}

// ---------------- fused reduce + FC2 + FC3 ----------------
__global__ __launch_bounds__(128) void k_fc23(const float* __restrict__ P,
        const float* __restrict__ b1, const float* __restrict__ W2,
        const float* __restrict__ b2, const float* __restrict__ W3,
        const float* __restrict__ b3, float* __restrict__ out) {
    __shared__ float row[256];
    __shared__ float r2[128];
    const int m = blockIdx.x, j = threadIdx.x;
#pragma unroll
    for (int rep = 0; rep < 2; ++rep) {
        int k2 = j + rep * 128;
        float s = b1[k2];
#pragma unroll 8
        for (int kc = 0; kc < 128; ++kc)
            s += P[(size_t)kc * 16384 + m * 256 + k2];
        row[k2] = s;
    }
    __syncthreads();
    float acc = b2[j];
#pragma unroll 4
    for (int k = 0; k < 256; ++k)
        acc = fmaf(row[k], W2[k * 128 + j], acc);
    r2[j] = acc;
    __syncthreads();
    const int w = j >> 6, l = j & 63;
    float s2 = r2[l] * W3[l * 2 + w] + r2[l + 64] * W3[(l + 64) * 2 + w];
#pragma unroll
    for (int off = 32; off > 0; off >>= 1)
        s2 += __shfl_down(s2, off);
    if (l == 0) out[m * 2 + w] = s2 + b3[w];
}

// ---------------- launch ----------------

extern "C" void kernel_launch(void* const* d_in, const int* in_sizes, int n_in,
                              void* d_out, int out_size, void* d_ws, size_t ws_size,
                              hipStream_t stream) {
    float* outp = (float*)d_out;
    if (ws_size < (size_t)WS_FLOATS * sizeof(float)) {
        k_zero_out<<<(out_size + 255) / 256, 256, 0, stream>>>(outp, out_size);
        return;
    }

    const float* x  = (const float*)d_in[0];
    const int*   ei = (const int*)d_in[1];
    const float* ew = (const float*)d_in[2];
    const float* cW[6] = {(const float*)d_in[3], (const float*)d_in[5],
                          (const float*)d_in[7], (const float*)d_in[9],
                          (const float*)d_in[11], (const float*)d_in[13]};
    const float* cb[6] = {(const float*)d_in[4], (const float*)d_in[6],
                          (const float*)d_in[8], (const float*)d_in[10],
                          (const float*)d_in[12], (const float*)d_in[14]};
    const float* fc1W = (const float*)d_in[15];
    const float* fc1b = (const float*)d_in[16];
    const float* fc2W = (const float*)d_in[17];
    const float* fc2b = (const float*)d_in[18];
    const float* fc3W = (const float*)d_in[19];
    const float* fc3b = (const float*)d_in[20];

    float*    ws   = (float*)d_ws;
    float*    Lhat = ws + OFF_LHAT;
    unsigned* Lp   = (unsigned*)(ws + OFF_LP);
    float*    deg  = ws + OFF_DEG;
    float*    Hp0  = ws + OFF_HP0;
    float*    Hp1  = ws + OFF_HP1;
    unsigned* Gp   = (unsigned*)(ws + OFF_GP);
    float*    F0   = ws + OFF_F0;
    float*    P    = ws + OFF_GP;   // fc1 partials alias GP+F0 (dead then)

    // build dense Lhat, split to f16 hi/lo planes
    k_zero_range<<<(OFF_DEG + 512 + 255) / 256, 256, 0, stream>>>(ws, OFF_DEG + 512);
    k_deg<<<EE / 256, 256, 0, stream>>>(ei, ew, deg);
    k_dinv<<<1, 512, 0, stream>>>(deg);
    k_build<<<EE / 256, 256, 0, stream>>>(ei, ew, deg, Lhat);
    k_splitL<<<NN * NN / 256, 256, 0, stream>>>(Lhat, Lp);

    dim3 pgrid(32, 8, 2);
    // layer 1 (CIN=50, from x)
    k_small<TT, 0><<<512, 256, 0, stream>>>(x, nullptr, cW[0], cb[0], Gp, F0);
    k_prop_mfma<<<pgrid, 256, 0, stream>>>(Lp, Gp, F0, Hp0, Hp1);
    // layers 2..6 (consumer combines Hp0+Hp1 and applies relu)
    k_small<FF, 1><<<512, 256, 0, stream>>>(Hp0, Hp1, cW[1], cb[1], Gp, F0);
    k_prop_mfma<<<pgrid, 256, 0, stream>>>(Lp, Gp, F0, Hp0, Hp1);
    k_small<FF, 1><<<512, 256, 0, stream>>>(Hp0, Hp1, cW[2], cb[2], Gp, F0);
    k_prop_mfma<<<pgrid, 256, 0, stream>>>(Lp, Gp, F0, Hp0, Hp1);
    k_small<FF, 1><<<512, 256, 0, stream>>>(Hp0, Hp1, cW[3], cb[3], Gp, F0);
    k_prop_mfma<<<pgrid, 256, 0, stream>>>(Lp, Gp, F0, Hp0, Hp1);
    k_small<FF, 1><<<512, 256, 0, stream>>>(Hp0, Hp1, cW[4], cb[4], Gp, F0);
    k_prop_mfma<<<pgrid, 256, 0, stream>>>(Lp, Gp, F0, Hp0, Hp1);
    k_small<FF, 1><<<512, 256, 0, stream>>>(Hp0, Hp1, cW[5], cb[5], Gp, F0);
    k_prop_mfma<<<pgrid, 256, 0, stream>>>(Lp, Gp, F0, Hp0, Hp1);

    // FC head (fc1 combines Hp0+Hp1 without relu — matches reference)
    dim3 fgrid(8, 128);
    k_fc1<<<fgrid, 256, 0, stream>>>(Hp0, Hp1, fc1W, P);
    k_fc23<<<64, 128, 0, stream>>>(P, fc1b, fc2W, fc2b, fc3W, fc3b, outp);
}